// Round 17
// baseline (1225.141 us; speedup 1.0000x reference)
//
#include <hip/hip_runtime.h>
#include <hip/hip_bf16.h>

typedef __attribute__((ext_vector_type(4))) float f32x4;
typedef __attribute__((ext_vector_type(4))) unsigned int u32x4;
typedef __attribute__((ext_vector_type(8))) __bf16 bf16x8;

#define DEV static __device__ __forceinline__
#define CFENCE() asm volatile("" ::: "memory")

DEV unsigned short f2bf(float f) {
  unsigned u = __builtin_bit_cast(unsigned, f);
  u += 0x7fffu + ((u >> 16) & 1u);
  return (unsigned short)(u >> 16);
}
DEV float bf2f(unsigned short b) {
  return __builtin_bit_cast(float, ((unsigned)b) << 16);
}
DEV unsigned pk2(float a, float b) {
  return (unsigned)f2bf(a) | ((unsigned)f2bf(b) << 16);
}
DEV unsigned cvtpk(float lo, float hi) {
  unsigned r;
  asm("v_cvt_pk_bf16_f32 %0, %1, %2" : "=v"(r) : "v"(lo), "v"(hi));
  return r;
}
DEV float fexp2(float x) {
  float r;
  asm("v_exp_f32 %0, %1" : "=v"(r) : "v"(x));
  return r;
}
// sigmoid-approx gelu: x * sigmoid(1.702 x)
DEV float gelu_s(float x) {
  float e = fexp2(-2.45562457f * x);  // exp(-1.702 x)
  return x * __builtin_amdgcn_rcpf(1.f + e);
}
DEV f32x4 mfma16(u32x4 a, u32x4 b, f32x4 c) {
  return __builtin_amdgcn_mfma_f32_16x16x32_bf16(
      __builtin_bit_cast(bf16x8, a), __builtin_bit_cast(bf16x8, b), c, 0, 0, 0);
}
DEV float ssq8(u32x4 c) {
  float s = 0.f;
#pragma unroll
  for (int e = 0; e < 4; e++) {
    float lo = __builtin_bit_cast(float, c[e] << 16);
    float hi = __builtin_bit_cast(float, c[e] & 0xffff0000u);
    s += lo * lo + hi * hi;
  }
  return s;
}
DEV void gload16(const unsigned short* g, unsigned short* l) {
  __builtin_amdgcn_global_load_lds(
      (const __attribute__((address_space(1))) unsigned int*)g,
      (__attribute__((address_space(3))) unsigned int*)l, 16, 0, 0);
}

// ---------------------------------------------------------------------------
// 256x256 bf16 GEMM, BK=32, double-buffered, 64 KB LDS -> 2 blocks/CU.
// Per K-tile: ONE vmcnt(0) + ONE barrier + stage(kt+1) + 12 frag reads +
// 32 MFMA + lgkm drain. Cross-block co-residency hides the sync stalls.
// r5-verified BK=32 bank mappings (src (l&3)^((l>>3)&3); read lg^((lr>>1)&3)).
// EPI: 0 = bf16, 1 = gelu(sigmoid) -> bf16. Two-pass coalesced C epilogue.
// ---------------------------------------------------------------------------
template <int EPI>
__global__ __launch_bounds__(512, 2) void gemm8(
    const unsigned short* __restrict__ A, const unsigned short* __restrict__ B,
    const float* __restrict__ bias, unsigned short* __restrict__ C,
    int Nc, int K, int nblocks) {
  __shared__ __align__(16) unsigned char smem[65536];
  unsigned short* As0 = (unsigned short*)smem;            // 2 bufs x 16 KB
  unsigned short* Bs0 = (unsigned short*)(smem + 32768);  // 2 bufs x 16 KB
  const int bid = blockIdx.x;
  const int mchunk = (gridDim.x >> 3) / nblocks;
  const int xcd = bid & 7, idx = bid >> 3;
  const int nb = idx % nblocks, ml = idx / nblocks;
  const int m0 = (xcd * mchunk + ml) * 256, n0 = nb * 256;
  const int tid = threadIdx.x, w = tid >> 6, l = tid & 63;
  const int lr = l & 15, lg = l >> 4;
  const int wm = (w >> 2) * 128, wn = (w & 3) * 64;
  const int rs = l >> 2;
  const int gs = ((l & 3) ^ ((l >> 3) & 3)) * 8;   // pre-swizzled src granule
  const int gsw = (lg ^ ((lr >> 1) & 3)) * 8;      // swizzled read granule
  const int NT = K >> 5;

  auto stage = [&](int p, int kt) {
#pragma unroll
    for (int j = 0; j < 2; j++) {
      int rb = j * 128 + w * 16;
      gload16(A + (size_t)(m0 + rb + rs) * K + kt * 32 + gs,
              As0 + p * 8192 + rb * 32);
      gload16(B + (size_t)(n0 + rb + rs) * K + kt * 32 + gs,
              Bs0 + p * 8192 + rb * 32);
    }
  };

  const f32x4 z4 = {0.f, 0.f, 0.f, 0.f};
  f32x4 acc[8][4];
#pragma unroll
  for (int i = 0; i < 8; i++)
#pragma unroll
    for (int j = 0; j < 4; j++) acc[i][j] = z4;
  u32x4 af[8], bf[4];

  stage(0, 0);
  for (int kt = 0; kt < NT; ++kt) {
    const int p = kt & 1;
    asm volatile("s_waitcnt vmcnt(0)" ::: "memory");  // kt's 4 loads landed
    __builtin_amdgcn_s_barrier();                     // + all waves' lgkm done
    CFENCE();
    if (kt + 1 < NT) stage(p ^ 1, kt + 1);            // overlaps below
#pragma unroll
    for (int ni = 0; ni < 4; ni++)
      bf[ni] = *(const u32x4*)&Bs0[p * 8192 + (wn + ni * 16 + lr) * 32 + gsw];
#pragma unroll
    for (int mi = 0; mi < 8; mi++)
      af[mi] = *(const u32x4*)&As0[p * 8192 + (wm + mi * 16 + lr) * 32 + gsw];
    __builtin_amdgcn_s_setprio(1);
#pragma unroll
    for (int mi = 0; mi < 8; mi++)
#pragma unroll
      for (int ni = 0; ni < 4; ni++)
        acc[mi][ni] = mfma16(bf[ni], af[mi], acc[mi][ni]);
    __builtin_amdgcn_s_setprio(0);
    asm volatile("s_waitcnt lgkmcnt(0)" ::: "memory");  // frags in regs (WAR)
    CFENCE();
  }

  // ---- two-pass coalesced epilogue: 128 rows x 512 B per pass (64 KB) ----
#pragma unroll
  for (int half = 0; half < 2; half++) {
    __syncthreads();
    if ((w >> 2) == half) {
#pragma unroll
      for (int mi = 0; mi < 8; mi++) {
        int rl = mi * 16 + lr;  // local row 0..127 (wm local part)
        int msw = rl & 7;
#pragma unroll
        for (int ni = 0; ni < 4; ni++) {
          f32x4 v = acc[mi][ni];
          f32x4 bv = *(const f32x4*)&bias[n0 + wn + ni * 16 + lg * 4];
#pragma unroll
          for (int r = 0; r < 4; r++) {
            float t = v[r] + bv[r];
            if (EPI == 1) t = gelu_s(t);
            v[r] = t;
          }
          int nbyte = (wn + ni * 16 + lg * 4) * 2;
          int addr = rl * 512 + ((((nbyte >> 4) ^ msw) << 4) | (nbyte & 8));
          *(uint2*)(smem + addr) =
              make_uint2(cvtpk(v[0], v[1]), cvtpk(v[2], v[3]));
        }
      }
    }
    __syncthreads();
#pragma unroll
    for (int c = 0; c < 8; c++) {
      int mloc = w * 16 + c * 2 + (l >> 5);
      int h = l & 31;
      u32x4 v = *(const u32x4*)(smem + mloc * 512 + ((h ^ (mloc & 7)) << 4));
      int n = n0 + h * 8;
      if (n < Nc)
        *(u32x4*)&C[(size_t)(m0 + half * 128 + mloc) * Nc + n] = v;
    }
  }
}

// ---------------------------------------------------------------------------
// Fused GEMM (BM=128, BN=384 full-row) + LayerNorm + residual.
// BK=32, double-buffered, 64 KB LDS -> 2 blocks/CU; same minimal sync.
// MODE 0 (proj+LN1): out_bf16[ungather(m)] = bf16(resf + LN(A@B^T+bias))
// MODE 1 (fc2+LN2):  out_f32[m] = bf2f(resb[m]) + LN(A@B^T+bias)
// ---------------------------------------------------------------------------
template <int MODE>
__global__ __launch_bounds__(512, 2) void gemm_ln8(
    const unsigned short* __restrict__ A, const unsigned short* __restrict__ Bw,
    const float* __restrict__ bias, const float* __restrict__ resf,
    const unsigned short* __restrict__ resb, const float* __restrict__ nw,
    const float* __restrict__ nb, unsigned short* __restrict__ outb,
    float* __restrict__ outf, int K) {
  __shared__ __align__(16) unsigned short As[2][128 * 32];  // 16 KB
  __shared__ __align__(16) unsigned short Bs[2][384 * 32];  // 48 KB
  const int bid = blockIdx.x;
  const int swz = (bid & 7) * (gridDim.x >> 3) + (bid >> 3);
  const int m0 = swz * 128;
  const int tid = threadIdx.x, w = tid >> 6, l = tid & 63;
  const int lr = l & 15, lg = l >> 4;
  const int wm = (w >> 2) * 64, wn = (w & 3) * 96;
  const int rs = l >> 2;
  const int gs = ((l & 3) ^ ((l >> 3) & 3)) * 8;
  const int gsw = (lg ^ ((lr >> 1) & 3)) * 8;
  const int NT = K >> 5;

  auto stage = [&](int p, int kt) {
    gload16(A + (size_t)(m0 + w * 16 + rs) * K + kt * 32 + gs,
            &As[p][(w * 16) * 32]);
#pragma unroll
    for (int j = 0; j < 3; j++) {
      int rb = j * 128 + w * 16;
      gload16(Bw + (size_t)(rb + rs) * K + kt * 32 + gs, &Bs[p][rb * 32]);
    }
  };

  const f32x4 z4 = {0.f, 0.f, 0.f, 0.f};
  f32x4 acc[4][6];
#pragma unroll
  for (int i = 0; i < 4; i++)
#pragma unroll
    for (int j = 0; j < 6; j++) acc[i][j] = z4;
  u32x4 af[4], bf[6];

  stage(0, 0);
  for (int kt = 0; kt < NT; ++kt) {
    const int p = kt & 1;
    asm volatile("s_waitcnt vmcnt(0)" ::: "memory");
    __builtin_amdgcn_s_barrier();
    CFENCE();
    if (kt + 1 < NT) stage(p ^ 1, kt + 1);
#pragma unroll
    for (int nj = 0; nj < 6; nj++)
      bf[nj] = *(const u32x4*)&Bs[p][(wn + nj * 16 + lr) * 32 + gsw];
#pragma unroll
    for (int mi = 0; mi < 4; mi++)
      af[mi] = *(const u32x4*)&As[p][(wm + mi * 16 + lr) * 32 + gsw];
    __builtin_amdgcn_s_setprio(1);
#pragma unroll
    for (int mi = 0; mi < 4; mi++)
#pragma unroll
      for (int nj = 0; nj < 6; nj++)
        acc[mi][nj] = mfma16(af[mi], bf[nj], acc[mi][nj]);
    __builtin_amdgcn_s_setprio(0);
    asm volatile("s_waitcnt lgkmcnt(0)" ::: "memory");
    CFENCE();
  }

  // ---- epilogue: bias, cross-wave LN stats (alias As[0]), residual ----
  __syncthreads();
  float bcol[6];
#pragma unroll
  for (int j = 0; j < 6; j++) bcol[j] = bias[wn + j * 16 + lr];
#pragma unroll
  for (int i = 0; i < 4; i++)
#pragma unroll
    for (int j = 0; j < 6; j++)
#pragma unroll
      for (int r = 0; r < 4; r++) acc[i][j][r] += bcol[j];

  float* psum = (float*)(&As[0][0]);     // [4][128]
  float* psq  = (float*)(&As[0][1024]);  // [4][128]
  const int wn4 = w & 3;
#pragma unroll
  for (int i = 0; i < 4; i++)
#pragma unroll
    for (int r = 0; r < 4; r++) {
      float s1 = 0.f, s2 = 0.f;
#pragma unroll
      for (int j = 0; j < 6; j++) {
        float v = acc[i][j][r];
        s1 += v;
        s2 += v * v;
      }
#pragma unroll
      for (int d = 1; d < 16; d <<= 1) {
        s1 += __shfl_xor(s1, d, 64);
        s2 += __shfl_xor(s2, d, 64);
      }
      if (lr == 0) {
        int row = wm + i * 16 + lg * 4 + r;
        psum[wn4 * 128 + row] = s1;
        psq[wn4 * 128 + row] = s2;
      }
    }
  __syncthreads();

  float wcol[6], b2col[6];
#pragma unroll
  for (int j = 0; j < 6; j++) {
    int col = wn + j * 16 + lr;
    wcol[j] = nw[col];
    b2col[j] = nb[col];
  }
#pragma unroll
  for (int i = 0; i < 4; i++)
#pragma unroll
    for (int r = 0; r < 4; r++) {
      int row = wm + i * 16 + lg * 4 + r;
      float sum = psum[row] + psum[128 + row] + psum[256 + row] + psum[384 + row];
      float sq = psq[row] + psq[128 + row] + psq[256 + row] + psq[384 + row];
      float mu = sum * (1.f / 384.f);
      float rstd = rsqrtf(sq * (1.f / 384.f) - mu * mu + 1e-5f);
      size_t nbase;
      if (MODE == 0) {
        int mrow = m0 + row;
        int bb = mrow >> 12, widx = (mrow >> 6) & 63, tt = mrow & 63;
        int yy = (((widx >> 3) << 3) + (tt >> 3) + 4) & 63;
        int xx = (((widx & 7) << 3) + (tt & 7) + 4) & 63;
        nbase = (size_t)((bb << 12) | (yy << 6) | xx) * 384;
      } else {
        nbase = (size_t)(m0 + row) * 384;
      }
#pragma unroll
      for (int j = 0; j < 6; j++) {
        int col = wn + j * 16 + lr;
        float v = (acc[i][j][r] - mu) * rstd * wcol[j] + b2col[j];
        if (MODE == 0) {
          outb[nbase + col] = f2bf(resf[nbase + col] + v);
        } else {
          outf[nbase + col] = bf2f(resb[nbase + col]) + v;
        }
      }
    }
}

// ---------------------------------------------------------------------------
// Attention: 4 waves/block, wave = one head; qkv row stride 1152.
// ---------------------------------------------------------------------------
__global__ __launch_bounds__(256, 4) void attn_win(
    const unsigned short* __restrict__ qkv, const float* __restrict__ btab2,
    const float* __restrict__ lscale, unsigned short* __restrict__ aout) {
  __shared__ __align__(16) unsigned short vT[4][32 * 72];
  __shared__ __align__(16) float rnk[4][64];
  const int w = blockIdx.x;
  const int wv = threadIdx.x >> 6, l = threadIdx.x & 63;
  const int h = blockIdx.y * 4 + wv;
  const int lr = l & 15, lg = l >> 4;
  const size_t base = (size_t)w * 64 * 1152 + h * 32;
  const f32x4 z4 = {0.f, 0.f, 0.f, 0.f};

  {
    const u32x4* vp = (const u32x4*)(qkv + base + (size_t)l * 1152 + 768);
#pragma unroll
    for (int c4 = 0; c4 < 4; c4++) {
      u32x4 c = vp[c4];
#pragma unroll
      for (int e = 0; e < 4; e++) {
        vT[wv][(c4 * 8 + e * 2) * 72 + l] = (unsigned short)(c[e] & 0xffffu);
        vT[wv][(c4 * 8 + e * 2 + 1) * 72 + l] = (unsigned short)(c[e] >> 16);
      }
    }
  }
  u32x4 kf[4];
#pragma unroll
  for (int tj = 0; tj < 4; tj++) {
    kf[tj] = *(const u32x4*)(qkv + base + (size_t)(tj * 16 + lr) * 1152 + 384 + lg * 8);
    float s = ssq8(kf[tj]);
    s += __shfl_xor(s, 16, 64);
    s += __shfl_xor(s, 32, 64);
    if (lg == 0) rnk[wv][tj * 16 + lr] = rsqrtf(fmaxf(s, 1e-24f));
  }
  u32x4 qf[4];
  float rnq[4];
#pragma unroll
  for (int ti = 0; ti < 4; ti++) {
    qf[ti] = *(const u32x4*)(qkv + base + (size_t)(ti * 16 + lr) * 1152 + lg * 8);
    float s = ssq8(qf[ti]);
    s += __shfl_xor(s, 16, 64);
    s += __shfl_xor(s, 32, 64);
    rnq[ti] = rsqrtf(fmaxf(s, 1e-24f));
  }
  __syncthreads();

  u32x4 vb[2][2];
#pragma unroll
  for (int kc = 0; kc < 2; kc++)
#pragma unroll
    for (int tj2 = 0; tj2 < 2; tj2++)
      vb[kc][tj2] = *(const u32x4*)(&vT[wv][(tj2 * 16 + lr) * 72 + kc * 32 + lg * 8]);

  const float scl2 = expf(fminf(lscale[h], 4.6051702f)) * 1.44269504f;
  const int wt = ((((w >> 3) & 7) == 7) ? 2 : 0) | (((w & 7) == 7) ? 1 : 0);
  const float* tabh = btab2 + (((size_t)wt * 12 + h) << 12);
  const int s0l = lr + ((l & 16) ? 32 : 0);
  const int s1l = s0l + 16;
  const bool hi = (l & 32) != 0;

#pragma unroll
  for (int ti = 0; ti < 4; ti++) {
    f32x4 sv[4];
#pragma unroll
    for (int tj = 0; tj < 4; tj++) sv[tj] = mfma16(kf[tj], qf[ti], z4);
    const float* tab = tabh + ((ti * 16 + lr) << 6);
    const float cb = rnq[ti] * scl2;
    f32x4 val[4];
    float m = -1e30f;
#pragma unroll
    for (int tj = 0; tj < 4; tj++) {
      f32x4 rk4 = *(const f32x4*)(&rnk[wv][tj * 16 + lg * 4]);
      f32x4 t4 = *(const f32x4*)(tab + tj * 16 + lg * 4);
#pragma unroll
      for (int r = 0; r < 4; r++) {
        float v = sv[tj][r] * (cb * rk4[r]) + t4[r];
        val[tj][r] = v;
        m = fmaxf(m, v);
      }
    }
    m = fmaxf(m, __shfl_xor(m, 16, 64));
    m = fmaxf(m, __shfl_xor(m, 32, 64));
    float den = 0.f;
#pragma unroll
    for (int tj = 0; tj < 4; tj++)
#pragma unroll
      for (int r = 0; r < 4; r++) {
        float p = fexp2(val[tj][r] - m);
        val[tj][r] = p;
        den += p;
      }
    den += __shfl_xor(den, 16, 64);
    den += __shfl_xor(den, 32, 64);
    float rden = 1.f / den;
#pragma unroll
    for (int tj = 0; tj < 4; tj++)
#pragma unroll
      for (int r = 0; r < 4; r++) val[tj][r] *= rden;

    f32x4 o[2] = {z4, z4};
#pragma unroll
    for (int kc = 0; kc < 2; kc++) {
      unsigned yA0 = cvtpk(val[2 * kc][0], val[2 * kc][1]);
      unsigned yA1 = cvtpk(val[2 * kc][2], val[2 * kc][3]);
      unsigned yB0 = cvtpk(val[2 * kc + 1][0], val[2 * kc + 1][1]);
      unsigned yB1 = cvtpk(val[2 * kc + 1][2], val[2 * kc + 1][3]);
      unsigned a0 = __shfl((int)yA0, s0l, 64), b0 = __shfl((int)yB0, s0l, 64);
      unsigned a1 = __shfl((int)yA1, s0l, 64), b1 = __shfl((int)yB1, s0l, 64);
      unsigned a2 = __shfl((int)yA0, s1l, 64), b2 = __shfl((int)yB0, s1l, 64);
      unsigned a3 = __shfl((int)yA1, s1l, 64), b3 = __shfl((int)yB1, s1l, 64);
      u32x4 pa = {hi ? b0 : a0, hi ? b1 : a1, hi ? b2 : a2, hi ? b3 : a3};
#pragma unroll
      for (int tj2 = 0; tj2 < 2; tj2++) o[tj2] = mfma16(pa, vb[kc][tj2], o[tj2]);
    }
#pragma unroll
    for (int tj2 = 0; tj2 < 2; tj2++)
#pragma unroll
      for (int r = 0; r < 4; r++)
        aout[(size_t)(w * 64 + ti * 16 + lg * 4 + r) * 384 + h * 32 + tj2 * 16 + lr] =
            f2bf(o[tj2][r]);
  }
}

// ---------------------------------------------------------------------------
// Fused pre-pass: gather_cvt + weight prep + btab2 in one launch.
// ---------------------------------------------------------------------------
__global__ __launch_bounds__(256) void prepass_kernel(
    const float* __restrict__ x, unsigned short* __restrict__ xb,
    const float* __restrict__ qkv_w, const float* __restrict__ proj_w,
    const float* __restrict__ w1, const float* __restrict__ w2,
    const float* __restrict__ qkv_b, unsigned short* __restrict__ wqb,
    unsigned short* __restrict__ wpb, unsigned short* __restrict__ w1b,
    unsigned short* __restrict__ w2b, float* __restrict__ qbp,
    const float* __restrict__ mw1, const float* __restrict__ mb1,
    const float* __restrict__ mw2, const float* __restrict__ mb2,
    float* __restrict__ btab2) {
  const int blk = blockIdx.x;
  if (blk < 32768) {
    int wv = threadIdx.x >> 6, l = threadIdx.x & 63;
    int m = blk * 4 + wv;
    int w = m >> 6, t = m & 63;
    int b = w >> 6, wy = (w >> 3) & 7, wx = w & 7;
    int oy = (wy * 8 + (t >> 3) + 4) & 63;
    int ox = (wx * 8 + (t & 7) + 4) & 63;
    const float2* src =
        (const float2*)(x + (size_t)((((b << 6) | oy) << 6) | ox) * 384 + l * 6);
    float2 f0 = src[0], f1 = src[1], f2 = src[2];
    unsigned* dst = (unsigned*)(xb + (size_t)m * 384 + l * 6);
    dst[0] = pk2(f0.x, f0.y);
    dst[1] = pk2(f1.x, f1.y);
    dst[2] = pk2(f2.x, f2.y);
  } else if (blk < 39877) {
    int i = (blk - 32768) * 256 + threadIdx.x;
    if (i < 491520) {
      wqb[i] = (i < 442368) ? f2bf(qkv_w[i]) : (unsigned short)0;
    } else if (i < 638976) {
      int j = i - 491520;
      wpb[j] = f2bf(proj_w[j]);
    } else if (i < 1228800) {
      int j = i - 638976;
      w1b[j] = f2bf(w1[j]);
    } else if (i < 1818624) {
      int j = i - 1228800;
      w2b[j] = f2bf(w2[j]);
    } else if (i < 1819904) {
      int j = i - 1818624;
      qbp[j] = (j < 1152) ? qkv_b[j] : 0.f;
    }
  } else {
    int p = (blk - 39877) * 256 + threadIdx.x;
    int i = p >> 6, j = p & 63;
    float dy = (float)((i >> 3) - (j >> 3));
    float dx = (float)((i & 7) - (j & 7));
    float r0 = (dy > 0.f ? 1.f : (dy < 0.f ? -1.f : 0.f)) * log1pf(fabsf(dy));
    float r1 = (dx > 0.f ? 1.f : (dx < 0.f ? -1.f : 0.f)) * log1pf(fabsf(dx));
    float acc[12];
#pragma unroll
    for (int hh = 0; hh < 12; hh++) acc[hh] = mb2[hh];
    for (int c = 0; c < 384; c++) {
      float hv = mw1[c * 2] * r0 + mw1[c * 2 + 1] * r1 + mb1[c];
      hv = fmaxf(hv, 0.f);
#pragma unroll
      for (int hh = 0; hh < 12; hh++) acc[hh] += hv * mw2[hh * 384 + c];
    }
    bool ddy = ((i >> 3) >= 4) != ((j >> 3) >= 4);
    bool ddx = ((i & 7) >= 4) != ((j & 7) >= 4);
    const float L2E = 1.44269504f;
#pragma unroll
    for (int wt = 0; wt < 4; wt++) {
      float mask = ((((wt >> 1) != 0) && ddy) || (((wt & 1) != 0) && ddx)) ? -100.f : 0.f;
#pragma unroll
      for (int hh = 0; hh < 12; hh++)
        btab2[(((size_t)wt * 12 + hh) << 12) + p] = (acc[hh] + mask) * L2E;
    }
  }
}

// ---------------------------------------------------------------------------
extern "C" void kernel_launch(void* const* d_in, const int* in_sizes, int n_in,
                              void* d_out, int out_size, void* d_ws,
                              size_t ws_size, hipStream_t stream) {
  (void)in_sizes; (void)n_in; (void)out_size; (void)ws_size;
  const float* x      = (const float*)d_in[0];
  const float* qkv_w  = (const float*)d_in[1];
  const float* qkv_b  = (const float*)d_in[2];
  const float* proj_w = (const float*)d_in[3];
  const float* proj_b = (const float*)d_in[4];
  const float* mw1    = (const float*)d_in[5];
  const float* mb1    = (const float*)d_in[6];
  const float* mw2    = (const float*)d_in[7];
  const float* mb2    = (const float*)d_in[8];
  const float* lsc    = (const float*)d_in[9];
  const float* n1w    = (const float*)d_in[10];
  const float* n1b    = (const float*)d_in[11];
  const float* w1     = (const float*)d_in[12];
  const float* b1     = (const float*)d_in[13];
  const float* w2     = (const float*)d_in[14];
  const float* b2     = (const float*)d_in[15];
  const float* n2w    = (const float*)d_in[16];
  const float* n2b    = (const float*)d_in[17];

  char* ws = (char*)d_ws;
  unsigned short* wqb  = (unsigned short*)(ws + 0);          // 1280x384 (padded)
  unsigned short* wpb  = (unsigned short*)(ws + 1048576);
  unsigned short* w1b  = (unsigned short*)(ws + 1441792);
  unsigned short* w2b  = (unsigned short*)(ws + 2621440);
  float* qbp           = (float*)(ws + 3801088);
  float* btab2         = (float*)(ws + 3866624);
  unsigned short* xb   = (unsigned short*)(ws + 4718592);    // 100.7 MB
  unsigned short* qkvb = (unsigned short*)(ws + 105381888);  // 302 MB
  unsigned short* att  = (unsigned short*)(ws + 440926208);  // 100.7 MB
  unsigned short* y1b  = xb;                                  // xb dead after QKV
  unsigned short* hb   = qkvb;  // 402.7 MB region, dead after proj
  float* yout = (float*)d_out;

  prepass_kernel<<<dim3(39893), 256, 0, stream>>>(
      x, xb, qkv_w, proj_w, w1, w2, qkv_b, wqb, wpb, w1b, w2b, qbp,
      mw1, mb1, mw2, mb2, btab2);

  // QKV: 131072 x 1152 (tiles cover 1280 via padded weights) x 384
  gemm8<0><<<dim3(2560), 512, 0, stream>>>(xb, wqb, qbp, qkvb, 1152, 384, 5);
  // attention: 4 heads/block
  attn_win<<<dim3(2048, 3), 256, 0, stream>>>(qkvb, btab2, lsc, att);
  // proj + LN1 + residual fused: att -> y1b
  gemm_ln8<0><<<dim3(1024), 512, 0, stream>>>(
      att, wpb, proj_b, x, nullptr, n1w, n1b, y1b, nullptr, 384);
  // fc1 (full M, single launch, sigmoid-gelu): y1b -> hb
  gemm8<1><<<dim3(3072), 512, 0, stream>>>(y1b, w1b, b1, hb, 1536, 384, 6);
  // fc2 + LN2 + residual fused (K=1536): hb -> yout
  gemm_ln8<1><<<dim3(1024), 512, 0, stream>>>(
      hb, w2b, b2, nullptr, y1b, n2w, n2b, nullptr, yout, 1536);
}

// Round 18
// 1039.359 us; speedup vs baseline: 1.1787x; 1.1787x over previous
//
#include <hip/hip_runtime.h>
#include <hip/hip_bf16.h>

typedef __attribute__((ext_vector_type(4))) float f32x4;
typedef __attribute__((ext_vector_type(4))) unsigned int u32x4;
typedef __attribute__((ext_vector_type(8))) __bf16 bf16x8;

#define DEV static __device__ __forceinline__
#define CFENCE() asm volatile("" ::: "memory")

DEV unsigned short f2bf(float f) {
  unsigned u = __builtin_bit_cast(unsigned, f);
  u += 0x7fffu + ((u >> 16) & 1u);
  return (unsigned short)(u >> 16);
}
DEV float bf2f(unsigned short b) {
  return __builtin_bit_cast(float, ((unsigned)b) << 16);
}
DEV unsigned pk2(float a, float b) {
  return (unsigned)f2bf(a) | ((unsigned)f2bf(b) << 16);
}
DEV unsigned cvtpk(float lo, float hi) {
  unsigned r;
  asm("v_cvt_pk_bf16_f32 %0, %1, %2" : "=v"(r) : "v"(lo), "v"(hi));
  return r;
}
DEV float fexp2(float x) {
  float r;
  asm("v_exp_f32 %0, %1" : "=v"(r) : "v"(x));
  return r;
}
// sigmoid-approx gelu: x * sigmoid(1.702 x)
DEV float gelu_s(float x) {
  float e = fexp2(-2.45562457f * x);  // exp(-1.702 x)
  return x * __builtin_amdgcn_rcpf(1.f + e);
}
DEV f32x4 mfma16(u32x4 a, u32x4 b, f32x4 c) {
  return __builtin_amdgcn_mfma_f32_16x16x32_bf16(
      __builtin_bit_cast(bf16x8, a), __builtin_bit_cast(bf16x8, b), c, 0, 0, 0);
}
DEV float ssq8(u32x4 c) {
  float s = 0.f;
#pragma unroll
  for (int e = 0; e < 4; e++) {
    float lo = __builtin_bit_cast(float, c[e] << 16);
    float hi = __builtin_bit_cast(float, c[e] & 0xffff0000u);
    s += lo * lo + hi * hi;
  }
  return s;
}
DEV void gload16(const unsigned short* g, unsigned short* l) {
  __builtin_amdgcn_global_load_lds(
      (const __attribute__((address_space(1))) unsigned int*)g,
      (__attribute__((address_space(3))) unsigned int*)l, 16, 0, 0);
}

// ---------------------------------------------------------------------------
// 8-phase 256x256 bf16 GEMM + LDS-staged coalesced epilogue (16x16x32 MFMA).
// BK=64, 2 buffers, counted vmcnt(8). EPI: 0 = bf16, 1 = gelu(sigmoid)->bf16.
// (r14/r16 structure, proven 1041-1047us.)
// ---------------------------------------------------------------------------
template <int EPI>
__global__ __launch_bounds__(512, 2) void gemm8(
    const unsigned short* __restrict__ A, const unsigned short* __restrict__ B,
    const float* __restrict__ bias, unsigned short* __restrict__ C,
    int Nc, int K, int nblocks) {
  __shared__ __align__(16) unsigned char smem[131072];
  unsigned short* As0 = (unsigned short*)smem;
  unsigned short* Bs0 = (unsigned short*)(smem + 65536);
  const int bid = blockIdx.x;
  const int mchunk = (gridDim.x >> 3) / nblocks;
  const int xcd = bid & 7, idx = bid >> 3;
  const int nb = idx % nblocks, ml = idx / nblocks;
  const int m0 = (xcd * mchunk + ml) * 256, n0 = nb * 256;
  const int tid = threadIdx.x, w = tid >> 6, l = tid & 63;
  const int lr = l & 15, lg = l >> 4;
  const int wm = (w >> 2) * 128, wn = (w & 3) * 64;
  const int srow = l >> 3;
  const int scol = ((l & 7) ^ srow) * 8;
  const int NT = K >> 6;

  auto stA = [&](int p, int kt, int half, int j) {
    int r = half * 128 + w * 16 + j * 8;
    gload16(A + (size_t)(m0 + r + srow) * K + kt * 64 + scol,
            As0 + p * 16384 + r * 64);
  };
  auto stB = [&](int p, int kt, int half, int j) {
    int r = half * 128 + w * 16 + j * 8;
    gload16(B + (size_t)(n0 + r + srow) * K + kt * 64 + scol,
            Bs0 + p * 16384 + r * 64);
  };

  const f32x4 z4 = {0.f, 0.f, 0.f, 0.f};
  f32x4 acc[8][4];
#pragma unroll
  for (int i = 0; i < 8; i++)
#pragma unroll
    for (int j = 0; j < 4; j++) acc[i][j] = z4;
  u32x4 af[8], bf[8];

#pragma unroll
  for (int ktp = 0; ktp < 2; ktp++) {
    stB(ktp, ktp, 0, 0); stB(ktp, ktp, 0, 1);
    stB(ktp, ktp, 1, 0); stB(ktp, ktp, 1, 1);
    stA(ktp, ktp, 0, 0); stA(ktp, ktp, 0, 1);
    stA(ktp, ktp, 1, 0); stA(ktp, ktp, 1, 1);
  }

  for (int kt = 0; kt < NT; ++kt) {
    const int p = kt & 1;
    if (kt + 1 < NT) {
      asm volatile("s_waitcnt vmcnt(8)" ::: "memory");
    } else {
      asm volatile("s_waitcnt vmcnt(0)" ::: "memory");
    }
    __builtin_amdgcn_s_barrier();
    CFENCE();

    // P0: issue all bf + af(m-half0) reads; MFMA a0 x n-half0
#pragma unroll
    for (int ni = 0; ni < 4; ni++)
#pragma unroll
      for (int ks = 0; ks < 2; ks++) {
        int R = wn + ni * 16 + lr;
        bf[ni * 2 + ks] = *(const u32x4*)&Bs0[p * 16384 + R * 64 +
                                             (((ks * 4 + lg) ^ (lr & 7)) * 8)];
      }
#pragma unroll
    for (int mi = 0; mi < 4; mi++)
#pragma unroll
      for (int ks = 0; ks < 2; ks++) {
        int R = wm + mi * 16 + lr;
        af[mi * 2 + ks] = *(const u32x4*)&As0[p * 16384 + R * 64 +
                                              (((ks * 4 + lg) ^ (lr & 7)) * 8)];
      }
    __builtin_amdgcn_s_setprio(1);
#pragma unroll
    for (int mi = 0; mi < 4; mi++)
#pragma unroll
      for (int ni = 0; ni < 2; ni++)
#pragma unroll
        for (int ks = 0; ks < 2; ks++)
          acc[mi][ni] = mfma16(bf[ni * 2 + ks], af[mi * 2 + ks], acc[mi][ni]);
    __builtin_amdgcn_s_setprio(0);
    asm volatile("s_waitcnt lgkmcnt(0)" ::: "memory");  // WAR: frags in regs
    __builtin_amdgcn_s_barrier();
    CFENCE();

    // P1: stage B-half0(kt+2); MFMA a0 x n-half1
    if (kt + 2 < NT) { stB(p, kt + 2, 0, 0); stB(p, kt + 2, 0, 1); }
    __builtin_amdgcn_s_setprio(1);
#pragma unroll
    for (int mi = 0; mi < 4; mi++)
#pragma unroll
      for (int ni = 0; ni < 2; ni++)
#pragma unroll
        for (int ks = 0; ks < 2; ks++)
          acc[mi][ni + 2] =
              mfma16(bf[(ni + 2) * 2 + ks], af[mi * 2 + ks], acc[mi][ni + 2]);
    __builtin_amdgcn_s_setprio(0);
    __builtin_amdgcn_s_barrier();
    CFENCE();

    // P2: read af(m-half1); stage B-half1; MFMA a1 x n-half0
#pragma unroll
    for (int mi = 0; mi < 4; mi++)
#pragma unroll
      for (int ks = 0; ks < 2; ks++) {
        int R = wm + 64 + mi * 16 + lr;
        af[mi * 2 + ks] = *(const u32x4*)&As0[p * 16384 + R * 64 +
                                              (((ks * 4 + lg) ^ (lr & 7)) * 8)];
      }
    if (kt + 2 < NT) { stB(p, kt + 2, 1, 0); stB(p, kt + 2, 1, 1); }
    __builtin_amdgcn_s_setprio(1);
#pragma unroll
    for (int mi = 0; mi < 4; mi++)
#pragma unroll
      for (int ni = 0; ni < 2; ni++)
#pragma unroll
        for (int ks = 0; ks < 2; ks++)
          acc[mi + 4][ni] =
              mfma16(bf[ni * 2 + ks], af[mi * 2 + ks], acc[mi + 4][ni]);
    __builtin_amdgcn_s_setprio(0);
    asm volatile("s_waitcnt lgkmcnt(0)" ::: "memory");  // WAR before A restage
    __builtin_amdgcn_s_barrier();
    CFENCE();

    // P3: stage A(kt+2); MFMA a1 x n-half1
    if (kt + 2 < NT) {
      stA(p, kt + 2, 0, 0); stA(p, kt + 2, 0, 1);
      stA(p, kt + 2, 1, 0); stA(p, kt + 2, 1, 1);
    }
    __builtin_amdgcn_s_setprio(1);
#pragma unroll
    for (int mi = 0; mi < 4; mi++)
#pragma unroll
      for (int ni = 0; ni < 2; ni++)
#pragma unroll
        for (int ks = 0; ks < 2; ks++)
          acc[mi + 4][ni + 2] =
              mfma16(bf[(ni + 2) * 2 + ks], af[mi * 2 + ks], acc[mi + 4][ni + 2]);
    __builtin_amdgcn_s_setprio(0);
  }

  __builtin_amdgcn_s_barrier();
  CFENCE();
#pragma unroll
  for (int mh = 0; mh < 2; mh++)
#pragma unroll
    for (int mi = 0; mi < 4; mi++) {
      int mloc = wm + mh * 64 + mi * 16 + lr;
      int msw = mloc & 7;
#pragma unroll
      for (int ni = 0; ni < 4; ni++) {
        f32x4 v = acc[mh * 4 + mi][ni];
        f32x4 bv = *(const f32x4*)&bias[n0 + wn + ni * 16 + lg * 4];
#pragma unroll
        for (int r = 0; r < 4; r++) {
          float t = v[r] + bv[r];
          if (EPI == 1) t = gelu_s(t);
          v[r] = t;
        }
        int nbyte = (wn + ni * 16 + lg * 4) * 2;
        int addr = mloc * 512 + ((((nbyte >> 4) ^ msw) << 4) | (nbyte & 8));
        *(uint2*)(smem + addr) = make_uint2(cvtpk(v[0], v[1]), cvtpk(v[2], v[3]));
      }
    }
  __syncthreads();
#pragma unroll
  for (int c = 0; c < 16; c++) {
    int m = w * 32 + c * 2 + (l >> 5);
    int h = l & 31;
    u32x4 v = *(const u32x4*)(smem + m * 512 + ((h ^ (m & 7)) << 4));
    int n = n0 + h * 8;
    if (n < Nc) *(u32x4*)&C[(size_t)(m0 + m) * Nc + n] = v;
  }
}

// ---------------------------------------------------------------------------
// Pipelined fused GEMM (BM=128, BN=384 full-row) + LayerNorm + residual.
// MODE 0 (proj+LN1), MODE 1 (fc2+LN2). r14/r16 structure.
// ---------------------------------------------------------------------------
template <int MODE>
__global__ __launch_bounds__(512, 2) void gemm_ln8(
    const unsigned short* __restrict__ A, const unsigned short* __restrict__ Bw,
    const float* __restrict__ bias, const float* __restrict__ resf,
    const unsigned short* __restrict__ resb, const float* __restrict__ nw,
    const float* __restrict__ nb, unsigned short* __restrict__ outb,
    float* __restrict__ outf, int K) {
  __shared__ __align__(16) unsigned short As[2][128 * 64];  // 32 KB
  __shared__ __align__(16) unsigned short Bs[2][384 * 64];  // 96 KB
  const int bid = blockIdx.x;
  const int swz = (bid & 7) * (gridDim.x >> 3) + (bid >> 3);
  const int m0 = swz * 128;
  const int tid = threadIdx.x, w = tid >> 6, l = tid & 63;
  const int lr = l & 15, lg = l >> 4;
  const int wm = (w >> 2) * 64, wn = (w & 3) * 96;
  const int srow = l >> 3;
  const int scol = ((l & 7) ^ srow) * 8;
  const int NT = K >> 6;

  auto stA = [&](int p, int kt, int j) {
    int r = w * 16 + j * 8;
    gload16(A + (size_t)(m0 + r + srow) * K + kt * 64 + scol, &As[p][r * 64]);
  };
  auto stB = [&](int p, int kt, int part, int j) {
    int r = part * 192 + w * 24 + j * 8;
    gload16(Bw + (size_t)(r + srow) * K + kt * 64 + scol, &Bs[p][r * 64]);
  };

  const f32x4 z4 = {0.f, 0.f, 0.f, 0.f};
  f32x4 acc[4][6];
#pragma unroll
  for (int i = 0; i < 4; i++)
#pragma unroll
    for (int j = 0; j < 6; j++) acc[i][j] = z4;
  u32x4 af[8], bf[12];

#pragma unroll
  for (int ktp = 0; ktp < 2; ktp++) {
    stB(ktp, ktp, 0, 0); stB(ktp, ktp, 0, 1); stB(ktp, ktp, 0, 2);
    stB(ktp, ktp, 1, 0); stB(ktp, ktp, 1, 1); stB(ktp, ktp, 1, 2);
    stA(ktp, ktp, 0); stA(ktp, ktp, 1);
  }

  for (int kt = 0; kt < NT; ++kt) {
    const int p = kt & 1;
    if (kt + 1 < NT) {
      asm volatile("s_waitcnt vmcnt(8)" ::: "memory");
    } else {
      asm volatile("s_waitcnt vmcnt(0)" ::: "memory");
    }
    __builtin_amdgcn_s_barrier();
    CFENCE();

    // P0: issue ALL fragment reads; MFMA nf{0,1}
#pragma unroll
    for (int nj = 0; nj < 6; nj++)
#pragma unroll
      for (int ks = 0; ks < 2; ks++) {
        int R = wn + nj * 16 + lr;
        bf[nj * 2 + ks] =
            *(const u32x4*)&Bs[p][R * 64 + (((ks * 4 + lg) ^ (lr & 7)) * 8)];
      }
#pragma unroll
    for (int mi = 0; mi < 4; mi++)
#pragma unroll
      for (int ks = 0; ks < 2; ks++) {
        int R = wm + mi * 16 + lr;
        af[mi * 2 + ks] =
            *(const u32x4*)&As[p][R * 64 + (((ks * 4 + lg) ^ (lr & 7)) * 8)];
      }
    __builtin_amdgcn_s_setprio(1);
#pragma unroll
    for (int mi = 0; mi < 4; mi++)
#pragma unroll
      for (int nj = 0; nj < 2; nj++)
#pragma unroll
        for (int ks = 0; ks < 2; ks++)
          acc[mi][nj] = mfma16(af[mi * 2 + ks], bf[nj * 2 + ks], acc[mi][nj]);
    __builtin_amdgcn_s_setprio(0);
    asm volatile("s_waitcnt lgkmcnt(0)" ::: "memory");  // WAR before restage
    __builtin_amdgcn_s_barrier();
    CFENCE();

    // P1: stage B part0 (kt+2); MFMA nf{2,3}
    if (kt + 2 < NT) {
      stB(p, kt + 2, 0, 0); stB(p, kt + 2, 0, 1); stB(p, kt + 2, 0, 2);
    }
    __builtin_amdgcn_s_setprio(1);
#pragma unroll
    for (int mi = 0; mi < 4; mi++)
#pragma unroll
      for (int nj = 2; nj < 4; nj++)
#pragma unroll
        for (int ks = 0; ks < 2; ks++)
          acc[mi][nj] = mfma16(af[mi * 2 + ks], bf[nj * 2 + ks], acc[mi][nj]);
    __builtin_amdgcn_s_setprio(0);
    __builtin_amdgcn_s_barrier();
    CFENCE();

    // P2: stage B part1 + A (kt+2); MFMA nf{4,5}
    if (kt + 2 < NT) {
      stB(p, kt + 2, 1, 0); stB(p, kt + 2, 1, 1); stB(p, kt + 2, 1, 2);
      stA(p, kt + 2, 0); stA(p, kt + 2, 1);
    }
    __builtin_amdgcn_s_setprio(1);
#pragma unroll
    for (int mi = 0; mi < 4; mi++)
#pragma unroll
      for (int nj = 4; nj < 6; nj++)
#pragma unroll
        for (int ks = 0; ks < 2; ks++)
          acc[mi][nj] = mfma16(af[mi * 2 + ks], bf[nj * 2 + ks], acc[mi][nj]);
    __builtin_amdgcn_s_setprio(0);
  }

  __syncthreads();
  float bcol[6];
#pragma unroll
  for (int j = 0; j < 6; j++) bcol[j] = bias[wn + j * 16 + lr];
#pragma unroll
  for (int i = 0; i < 4; i++)
#pragma unroll
    for (int j = 0; j < 6; j++)
#pragma unroll
      for (int r = 0; r < 4; r++) acc[i][j][r] += bcol[j];

  float* psum = (float*)(&As[0][0]);
  float* psq  = (float*)(&As[0][1024]);
  const int wn4 = w & 3;
#pragma unroll
  for (int i = 0; i < 4; i++)
#pragma unroll
    for (int r = 0; r < 4; r++) {
      float s1 = 0.f, s2 = 0.f;
#pragma unroll
      for (int j = 0; j < 6; j++) {
        float v = acc[i][j][r];
        s1 += v;
        s2 += v * v;
      }
#pragma unroll
      for (int d = 1; d < 16; d <<= 1) {
        s1 += __shfl_xor(s1, d, 64);
        s2 += __shfl_xor(s2, d, 64);
      }
      if (lr == 0) {
        int row = wm + i * 16 + lg * 4 + r;
        psum[wn4 * 128 + row] = s1;
        psq[wn4 * 128 + row] = s2;
      }
    }
  __syncthreads();

  float wcol[6], b2col[6];
#pragma unroll
  for (int j = 0; j < 6; j++) {
    int col = wn + j * 16 + lr;
    wcol[j] = nw[col];
    b2col[j] = nb[col];
  }
#pragma unroll
  for (int i = 0; i < 4; i++)
#pragma unroll
    for (int r = 0; r < 4; r++) {
      int row = wm + i * 16 + lg * 4 + r;
      float sum = psum[row] + psum[128 + row] + psum[256 + row] + psum[384 + row];
      float sq = psq[row] + psq[128 + row] + psq[256 + row] + psq[384 + row];
      float mu = sum * (1.f / 384.f);
      float rstd = rsqrtf(sq * (1.f / 384.f) - mu * mu + 1e-5f);
      size_t nbase;
      if (MODE == 0) {
        int mrow = m0 + row;
        int bb = mrow >> 12, widx = (mrow >> 6) & 63, tt = mrow & 63;
        int yy = (((widx >> 3) << 3) + (tt >> 3) + 4) & 63;
        int xx = (((widx & 7) << 3) + (tt & 7) + 4) & 63;
        nbase = (size_t)((bb << 12) | (yy << 6) | xx) * 384;
      } else {
        nbase = (size_t)(m0 + row) * 384;
      }
#pragma unroll
      for (int j = 0; j < 6; j++) {
        int col = wn + j * 16 + lr;
        float v = (acc[i][j][r] - mu) * rstd * wcol[j] + b2col[j];
        if (MODE == 0) {
          outb[nbase + col] = f2bf(resf[nbase + col] + v);
        } else {
          outf[nbase + col] = bf2f(resb[nbase + col]) + v;
        }
      }
    }
}

// ---------------------------------------------------------------------------
// Attention: 4 waves/block, wave = one head; qkv row stride 1152.
// ---------------------------------------------------------------------------
__global__ __launch_bounds__(256, 4) void attn_win(
    const unsigned short* __restrict__ qkv, const float* __restrict__ btab2,
    const float* __restrict__ lscale, unsigned short* __restrict__ aout) {
  __shared__ __align__(16) unsigned short vT[4][32 * 72];
  __shared__ __align__(16) float rnk[4][64];
  const int w = blockIdx.x;
  const int wv = threadIdx.x >> 6, l = threadIdx.x & 63;
  const int h = blockIdx.y * 4 + wv;
  const int lr = l & 15, lg = l >> 4;
  const size_t base = (size_t)w * 64 * 1152 + h * 32;
  const f32x4 z4 = {0.f, 0.f, 0.f, 0.f};

  {
    const u32x4* vp = (const u32x4*)(qkv + base + (size_t)l * 1152 + 768);
#pragma unroll
    for (int c4 = 0; c4 < 4; c4++) {
      u32x4 c = vp[c4];
#pragma unroll
      for (int e = 0; e < 4; e++) {
        vT[wv][(c4 * 8 + e * 2) * 72 + l] = (unsigned short)(c[e] & 0xffffu);
        vT[wv][(c4 * 8 + e * 2 + 1) * 72 + l] = (unsigned short)(c[e] >> 16);
      }
    }
  }
  u32x4 kf[4];
#pragma unroll
  for (int tj = 0; tj < 4; tj++) {
    kf[tj] = *(const u32x4*)(qkv + base + (size_t)(tj * 16 + lr) * 1152 + 384 + lg * 8);
    float s = ssq8(kf[tj]);
    s += __shfl_xor(s, 16, 64);
    s += __shfl_xor(s, 32, 64);
    if (lg == 0) rnk[wv][tj * 16 + lr] = rsqrtf(fmaxf(s, 1e-24f));
  }
  u32x4 qf[4];
  float rnq[4];
#pragma unroll
  for (int ti = 0; ti < 4; ti++) {
    qf[ti] = *(const u32x4*)(qkv + base + (size_t)(ti * 16 + lr) * 1152 + lg * 8);
    float s = ssq8(qf[ti]);
    s += __shfl_xor(s, 16, 64);
    s += __shfl_xor(s, 32, 64);
    rnq[ti] = rsqrtf(fmaxf(s, 1e-24f));
  }
  __syncthreads();

  u32x4 vb[2][2];
#pragma unroll
  for (int kc = 0; kc < 2; kc++)
#pragma unroll
    for (int tj2 = 0; tj2 < 2; tj2++)
      vb[kc][tj2] = *(const u32x4*)(&vT[wv][(tj2 * 16 + lr) * 72 + kc * 32 + lg * 8]);

  const float scl2 = expf(fminf(lscale[h], 4.6051702f)) * 1.44269504f;
  const int wt = ((((w >> 3) & 7) == 7) ? 2 : 0) | (((w & 7) == 7) ? 1 : 0);
  const float* tabh = btab2 + (((size_t)wt * 12 + h) << 12);
  const int s0l = lr + ((l & 16) ? 32 : 0);
  const int s1l = s0l + 16;
  const bool hi = (l & 32) != 0;

#pragma unroll
  for (int ti = 0; ti < 4; ti++) {
    f32x4 sv[4];
#pragma unroll
    for (int tj = 0; tj < 4; tj++) sv[tj] = mfma16(kf[tj], qf[ti], z4);
    const float* tab = tabh + ((ti * 16 + lr) << 6);
    const float cb = rnq[ti] * scl2;
    f32x4 val[4];
    float m = -1e30f;
#pragma unroll
    for (int tj = 0; tj < 4; tj++) {
      f32x4 rk4 = *(const f32x4*)(&rnk[wv][tj * 16 + lg * 4]);
      f32x4 t4 = *(const f32x4*)(tab + tj * 16 + lg * 4);
#pragma unroll
      for (int r = 0; r < 4; r++) {
        float v = sv[tj][r] * (cb * rk4[r]) + t4[r];
        val[tj][r] = v;
        m = fmaxf(m, v);
      }
    }
    m = fmaxf(m, __shfl_xor(m, 16, 64));
    m = fmaxf(m, __shfl_xor(m, 32, 64));
    float den = 0.f;
#pragma unroll
    for (int tj = 0; tj < 4; tj++)
#pragma unroll
      for (int r = 0; r < 4; r++) {
        float p = fexp2(val[tj][r] - m);
        val[tj][r] = p;
        den += p;
      }
    den += __shfl_xor(den, 16, 64);
    den += __shfl_xor(den, 32, 64);
    float rden = 1.f / den;
#pragma unroll
    for (int tj = 0; tj < 4; tj++)
#pragma unroll
      for (int r = 0; r < 4; r++) val[tj][r] *= rden;

    f32x4 o[2] = {z4, z4};
#pragma unroll
    for (int kc = 0; kc < 2; kc++) {
      unsigned yA0 = cvtpk(val[2 * kc][0], val[2 * kc][1]);
      unsigned yA1 = cvtpk(val[2 * kc][2], val[2 * kc][3]);
      unsigned yB0 = cvtpk(val[2 * kc + 1][0], val[2 * kc + 1][1]);
      unsigned yB1 = cvtpk(val[2 * kc + 1][2], val[2 * kc + 1][3]);
      unsigned a0 = __shfl((int)yA0, s0l, 64), b0 = __shfl((int)yB0, s0l, 64);
      unsigned a1 = __shfl((int)yA1, s0l, 64), b1 = __shfl((int)yB1, s0l, 64);
      unsigned a2 = __shfl((int)yA0, s1l, 64), b2 = __shfl((int)yB0, s1l, 64);
      unsigned a3 = __shfl((int)yA1, s1l, 64), b3 = __shfl((int)yB1, s1l, 64);
      u32x4 pa = {hi ? b0 : a0, hi ? b1 : a1, hi ? b2 : a2, hi ? b3 : a3};
#pragma unroll
      for (int tj2 = 0; tj2 < 2; tj2++) o[tj2] = mfma16(pa, vb[kc][tj2], o[tj2]);
    }
#pragma unroll
    for (int tj2 = 0; tj2 < 2; tj2++)
#pragma unroll
      for (int r = 0; r < 4; r++)
        aout[(size_t)(w * 64 + ti * 16 + lg * 4 + r) * 384 + h * 32 + tj2 * 16 + lr] =
            f2bf(o[tj2][r]);
  }
}

// ---------------------------------------------------------------------------
// Fused pre-pass: gather_cvt + weight prep + btab2 in one launch.
// ---------------------------------------------------------------------------
__global__ __launch_bounds__(256) void prepass_kernel(
    const float* __restrict__ x, unsigned short* __restrict__ xb,
    const float* __restrict__ qkv_w, const float* __restrict__ proj_w,
    const float* __restrict__ w1, const float* __restrict__ w2,
    const float* __restrict__ qkv_b, unsigned short* __restrict__ wqb,
    unsigned short* __restrict__ wpb, unsigned short* __restrict__ w1b,
    unsigned short* __restrict__ w2b, float* __restrict__ qbp,
    const float* __restrict__ mw1, const float* __restrict__ mb1,
    const float* __restrict__ mw2, const float* __restrict__ mb2,
    float* __restrict__ btab2) {
  const int blk = blockIdx.x;
  if (blk < 32768) {
    int wv = threadIdx.x >> 6, l = threadIdx.x & 63;
    int m = blk * 4 + wv;
    int w = m >> 6, t = m & 63;
    int b = w >> 6, wy = (w >> 3) & 7, wx = w & 7;
    int oy = (wy * 8 + (t >> 3) + 4) & 63;
    int ox = (wx * 8 + (t & 7) + 4) & 63;
    const float2* src =
        (const float2*)(x + (size_t)((((b << 6) | oy) << 6) | ox) * 384 + l * 6);
    float2 f0 = src[0], f1 = src[1], f2 = src[2];
    unsigned* dst = (unsigned*)(xb + (size_t)m * 384 + l * 6);
    dst[0] = pk2(f0.x, f0.y);
    dst[1] = pk2(f1.x, f1.y);
    dst[2] = pk2(f2.x, f2.y);
  } else if (blk < 39877) {
    int i = (blk - 32768) * 256 + threadIdx.x;
    if (i < 491520) {
      wqb[i] = (i < 442368) ? f2bf(qkv_w[i]) : (unsigned short)0;
    } else if (i < 638976) {
      int j = i - 491520;
      wpb[j] = f2bf(proj_w[j]);
    } else if (i < 1228800) {
      int j = i - 638976;
      w1b[j] = f2bf(w1[j]);
    } else if (i < 1818624) {
      int j = i - 1228800;
      w2b[j] = f2bf(w2[j]);
    } else if (i < 1819904) {
      int j = i - 1818624;
      qbp[j] = (j < 1152) ? qkv_b[j] : 0.f;
    }
  } else {
    int p = (blk - 39877) * 256 + threadIdx.x;
    int i = p >> 6, j = p & 63;
    float dy = (float)((i >> 3) - (j >> 3));
    float dx = (float)((i & 7) - (j & 7));
    float r0 = (dy > 0.f ? 1.f : (dy < 0.f ? -1.f : 0.f)) * log1pf(fabsf(dy));
    float r1 = (dx > 0.f ? 1.f : (dx < 0.f ? -1.f : 0.f)) * log1pf(fabsf(dx));
    float acc[12];
#pragma unroll
    for (int hh = 0; hh < 12; hh++) acc[hh] = mb2[hh];
    for (int c = 0; c < 384; c++) {
      float hv = mw1[c * 2] * r0 + mw1[c * 2 + 1] * r1 + mb1[c];
      hv = fmaxf(hv, 0.f);
#pragma unroll
      for (int hh = 0; hh < 12; hh++) acc[hh] += hv * mw2[hh * 384 + c];
    }
    bool ddy = ((i >> 3) >= 4) != ((j >> 3) >= 4);
    bool ddx = ((i & 7) >= 4) != ((j & 7) >= 4);
    const float L2E = 1.44269504f;
#pragma unroll
    for (int wt = 0; wt < 4; wt++) {
      float mask = ((((wt >> 1) != 0) && ddy) || (((wt & 1) != 0) && ddx)) ? -100.f : 0.f;
#pragma unroll
      for (int hh = 0; hh < 12; hh++)
        btab2[(((size_t)wt * 12 + hh) << 12) + p] = (acc[hh] + mask) * L2E;
    }
  }
}

// ---------------------------------------------------------------------------
extern "C" void kernel_launch(void* const* d_in, const int* in_sizes, int n_in,
                              void* d_out, int out_size, void* d_ws,
                              size_t ws_size, hipStream_t stream) {
  (void)in_sizes; (void)n_in; (void)out_size; (void)ws_size;
  const float* x      = (const float*)d_in[0];
  const float* qkv_w  = (const float*)d_in[1];
  const float* qkv_b  = (const float*)d_in[2];
  const float* proj_w = (const float*)d_in[3];
  const float* proj_b = (const float*)d_in[4];
  const float* mw1    = (const float*)d_in[5];
  const float* mb1    = (const float*)d_in[6];
  const float* mw2    = (const float*)d_in[7];
  const float* mb2    = (const float*)d_in[8];
  const float* lsc    = (const float*)d_in[9];
  const float* n1w    = (const float*)d_in[10];
  const float* n1b    = (const float*)d_in[11];
  const float* w1     = (const float*)d_in[12];
  const float* b1     = (const float*)d_in[13];
  const float* w2     = (const float*)d_in[14];
  const float* b2     = (const float*)d_in[15];
  const float* n2w    = (const float*)d_in[16];
  const float* n2b    = (const float*)d_in[17];

  char* ws = (char*)d_ws;
  unsigned short* wqb  = (unsigned short*)(ws + 0);          // 1280x384 (padded)
  unsigned short* wpb  = (unsigned short*)(ws + 1048576);
  unsigned short* w1b  = (unsigned short*)(ws + 1441792);
  unsigned short* w2b  = (unsigned short*)(ws + 2621440);
  float* qbp           = (float*)(ws + 3801088);
  float* btab2         = (float*)(ws + 3866624);
  unsigned short* xb   = (unsigned short*)(ws + 4718592);    // 100.7 MB
  unsigned short* qkvb = (unsigned short*)(ws + 105381888);  // 302 MB
  unsigned short* att  = (unsigned short*)(ws + 440926208);  // 100.7 MB
  unsigned short* y1b  = xb;                                  // xb dead after QKV
  unsigned short* hb   = qkvb;  // 402.7 MB region, dead after proj
  float* yout = (float*)d_out;

  prepass_kernel<<<dim3(39893), 256, 0, stream>>>(
      x, xb, qkv_w, proj_w, w1, w2, qkv_b, wqb, wpb, w1b, w2b, qbp,
      mw1, mb1, mw2, mb2, btab2);

  // QKV: 131072 x 1152 (tiles cover 1280 via padded weights) x 384
  gemm8<0><<<dim3(2560), 512, 0, stream>>>(xb, wqb, qbp, qkvb, 1152, 384, 5);
  // attention: 4 heads/block
  attn_win<<<dim3(2048, 3), 256, 0, stream>>>(qkvb, btab2, lsc, att);
  // proj + LN1 + residual fused: att -> y1b
  gemm_ln8<0><<<dim3(1024), 512, 0, stream>>>(
      att, wpb, proj_b, x, nullptr, n1w, n1b, y1b, nullptr, 384);
  // fc1 (full M, single launch, sigmoid-gelu): y1b -> hb
  gemm8<1><<<dim3(3072), 512, 0, stream>>>(y1b, w1b, b1, hb, 1536, 384, 6);
  // fc2 + LN2 + residual fused (K=1536): hb -> yout
  gemm_ln8<1><<<dim3(1024), 512, 0, stream>>>(
      hb, w2b, b2, nullptr, y1b, n2w, n2b, nullptr, yout, 1536);
}